// Round 9
// baseline (221.644 us; speedup 1.0000x reference)
//
#include <hip/hip_runtime.h>
#include <hip/hip_bf16.h>

#define BB 4
#define HH 16
#define SS 1024
#define DD 64
#define N4 4194304  // B*H*S*D
#define L2E 1.44269504f

typedef __attribute__((ext_vector_type(8))) short bf16x8;
typedef __attribute__((ext_vector_type(4))) float f32x4;

#define MFMA(A, B, C) __builtin_amdgcn_mfma_f32_16x16x32_bf16((A), (B), (C), 0, 0, 0)

__device__ inline float b2f(unsigned short u) { return __uint_as_float(((unsigned)u) << 16); }
__device__ inline unsigned short f2b(float f) {
  union { __hip_bfloat16 h; unsigned short u; } x;
  x.h = __float2bfloat16(f);
  return x.u;
}
__device__ inline unsigned pkbf(float a, float b) {
  return (unsigned)f2b(a) | ((unsigned)f2b(b) << 16);
}
__device__ inline bf16x8 pack8(float4 a, float4 b) {
  union { bf16x8 v; unsigned short u[8]; } x;
  x.u[0] = f2b(a.x); x.u[1] = f2b(a.y); x.u[2] = f2b(a.z); x.u[3] = f2b(a.w);
  x.u[4] = f2b(b.x); x.u[5] = f2b(b.y); x.u[6] = f2b(b.z); x.u[7] = f2b(b.w);
  return x.v;
}

// ---- k_prep: K->bf16 [b][t][d]; V->bf16 transposed [b][d][t]; W->bf16 transposed [h][e][d]
// grid 144 = 64 K-convert + 64 V-transpose + 16 W-transpose
__global__ __launch_bounds__(256) void k_prep(const float* __restrict__ key, const float* __restrict__ val,
                                              const float* __restrict__ wgt, __hip_bfloat16* __restrict__ Kb,
                                              __hip_bfloat16* __restrict__ VTb, __hip_bfloat16* __restrict__ WT) {
  const int bid = blockIdx.x, tid = threadIdx.x;
  if (bid < 64) {  // K convert: 64 blocks x 4096 elems
    size_t base = (size_t)bid * 4096 + (size_t)tid * 16;
#pragma unroll
    for (int j = 0; j < 4; j++) {
      float4 v = *(const float4*)(key + base + j * 4);
      ushort4 u;
      u.x = f2b(v.x); u.y = f2b(v.y); u.z = f2b(v.z); u.w = f2b(v.w);
      *(ushort4*)(Kb + base + j * 4) = u;
    }
    return;
  }
  __shared__ __hip_bfloat16 tl[64][72];
  const float* src;
  __hip_bfloat16* dst;
  int dstride;
  if (bid < 128) {  // V transpose: 64 blocks of 64x64 tiles
    int qq = bid - 64;
    int b2 = qq >> 4, t0 = (qq & 15) * 64;
    src = val + ((size_t)b2 * 1024 + t0) * 64;
    dst = VTb + (size_t)b2 * 65536 + t0;
    dstride = 1024;
  } else {  // W transpose per head: 16 blocks
    int h = bid - 128;
    src = wgt + (size_t)h * 4096;
    dst = WT + (size_t)h * 4096;
    dstride = 64;
  }
  int row = tid >> 2, cq = (tid & 3) * 16;
#pragma unroll
  for (int j = 0; j < 4; j++) {
    float4 v = *(const float4*)(src + (size_t)row * 64 + cq + j * 4);
    tl[cq + j * 4 + 0][row] = __float2bfloat16(v.x);
    tl[cq + j * 4 + 1][row] = __float2bfloat16(v.y);
    tl[cq + j * 4 + 2][row] = __float2bfloat16(v.z);
    tl[cq + j * 4 + 3][row] = __float2bfloat16(v.w);
  }
  __syncthreads();
#pragma unroll
  for (int j = 0; j < 2; j++) {
    bf16x8 a = *(bf16x8*)&tl[row][cq + j * 8];
    *(bf16x8*)(dst + (size_t)row * dstride + cq + j * 8) = a;
  }
}

// ---- k_attn: fused wq-proj + qk^T (MFMA) + cross-head softmax + PV (MFMA)
// block = (b, s-tile 16, t-chunk 256); 4 waves; wave w owns heads 4w..4w+3.
// 4 blocks/CU (LDS 39424B x 4 = 157.7KB). scale*log2e pre-folded into wq (bf16).
// kf for tile t+1 prefetched before the barrier so the barrier's vmcnt drain
// absorbs the load latency instead of QK stalling.
__global__ __launch_bounds__(256, 4) void k_attn(
    const float* __restrict__ q, const __hip_bfloat16* __restrict__ Kb,
    const __hip_bfloat16* __restrict__ VTb, const __hip_bfloat16* __restrict__ WT,
    const float* __restrict__ scale_p, __hip_bfloat16* __restrict__ dvp) {
  const int b = blockIdx.x, s0 = blockIdx.y << 4, tc = blockIdx.z;
  const int tid = threadIdx.x, lane = tid & 63, w = tid >> 6;
  const int lm = lane & 15, kg = lane >> 4;
  const float csl = (*scale_p) * L2E;

  __shared__ __align__(16) char smem_all[39424];
  float* sden = (float*)smem_all;              // 18944 B
  char* wv = smem_all + 18944 + w * 5120;      // wave-private 5120 B

  // ---- prologue: q B-frags (lane lm = s, k = d)
  bf16x8 qf[2];
#pragma unroll
  for (int ks = 0; ks < 2; ks++) {
    const float* qp = q + ((size_t)(b * SS + s0 + lm)) * DD + ks * 32 + kg * 8;
    qf[ks] = pack8(*(const float4*)qp, *(const float4*)(qp + 4));
  }
  // wq^T = mfma(WT, q) * scale * log2e: D row=e, col=s -> wave-LDS (XOR-swizzled) -> B-frags
  bf16x8 wqf[4][2];
#pragma unroll
  for (int i = 0; i < 4; i++) {
    const int h = w * 4 + i;
    f32x4 wd[4];
#pragma unroll
    for (int et = 0; et < 4; et++) wd[et] = (f32x4){0.f, 0.f, 0.f, 0.f};
#pragma unroll
    for (int et = 0; et < 4; et++)
#pragma unroll
      for (int ks = 0; ks < 2; ks++) {
        bf16x8 af = *(const bf16x8*)(WT + ((size_t)(h * 64 + et * 16 + lm)) * 64 + ks * 32 + kg * 8);
        wd[et] = MFMA(af, qf[ks], wd[et]);
      }
#pragma unroll
    for (int et = 0; et < 4; et++) {
      uint2 u;
      u.x = pkbf(wd[et][0] * csl, wd[et][1] * csl);
      u.y = pkbf(wd[et][2] * csl, wd[et][3] * csl);
      *(uint2*)(wv + lm * 128 + ((et * 32 + kg * 8) ^ ((lm & 7) << 4))) = u;
    }
    asm volatile("s_waitcnt lgkmcnt(0)" ::: "memory");
#pragma unroll
    for (int ks = 0; ks < 2; ks++)
      wqf[i][ks] = *(bf16x8*)(wv + lm * 128 + ((ks * 64 + kg * 16) ^ ((lm & 7) << 4)));
    asm volatile("" ::: "memory");
  }

  // ---- main loop over 32-t tiles (8 per chunk)
  f32x4 pv[4][4];
#pragma unroll
  for (int i = 0; i < 4; i++)
#pragma unroll
    for (int dt = 0; dt < 4; dt++) pv[i][dt] = (f32x4){0.f, 0.f, 0.f, 0.f};

  const __hip_bfloat16* Kbb = Kb + (size_t)b * (SS * DD);
  const __hip_bfloat16* Vbb = VTb + (size_t)b * (SS * DD);
  const int tbeg = tc * 256, tend = tbeg + 256;
  int buf = 0;
  bf16x8 kf[2][2], vf[4];
  // preload kf for first tile
#pragma unroll
  for (int tt = 0; tt < 2; tt++)
#pragma unroll
    for (int ks = 0; ks < 2; ks++)
      kf[tt][ks] = *(const bf16x8*)(Kbb + ((size_t)(tbeg + tt * 16 + lm)) * 64 + ks * 32 + kg * 8);

#pragma unroll 1
  for (int t0 = tbeg; t0 < tend; t0 += 32) {
    // vf for current tile (consumed at PV; latency covered by QK/exp phases + barrier)
#pragma unroll
    for (int dt = 0; dt < 4; dt++)
      vf[dt] = *(const bf16x8*)(Vbb + ((size_t)(dt * 16 + lm)) * 1024 + t0 + kg * 8);

    // qk^T: D row = t (4kg+r within tt), col = s (lm); scale pre-folded
    f32x4 qk[4][2];
#pragma unroll
    for (int i = 0; i < 4; i++)
#pragma unroll
      for (int tt = 0; tt < 2; tt++) qk[i][tt] = (f32x4){0.f, 0.f, 0.f, 0.f};
#pragma unroll
    for (int ks = 0; ks < 2; ks++)
#pragma unroll
      for (int i = 0; i < 4; i++)
#pragma unroll
        for (int tt = 0; tt < 2; tt++) qk[i][tt] = MFMA(kf[tt][ks], wqf[i][ks], qk[i][tt]);

    // e = exp2(qk), per-wave partial sums over 4 local heads (no max-sub: |qk| small)
    float ev[4][2][4];
    f32x4 l4[2];
    l4[0] = (f32x4){0.f, 0.f, 0.f, 0.f};
    l4[1] = (f32x4){0.f, 0.f, 0.f, 0.f};
#pragma unroll
    for (int i = 0; i < 4; i++)
#pragma unroll
      for (int tt = 0; tt < 2; tt++)
#pragma unroll
        for (int r = 0; r < 4; r++) {
          float e = exp2f(qk[i][tt][r]);
          ev[i][tt][r] = e;
          l4[tt][r] += e;
        }
    {
      // t = tt*16 + kg*4 + r
      const int sb = buf * 2368 + lm * 148 + w * 36 + kg * 4;
      *(f32x4*)&sden[sb + 0] = l4[0];
      *(f32x4*)&sden[sb + 16] = l4[1];
    }
    // prefetch kf for next tile (wraps on last iter; barrier drain absorbs latency)
    {
      int tn = (t0 + 32 < tend) ? t0 + 32 : tbeg;
#pragma unroll
      for (int tt = 0; tt < 2; tt++)
#pragma unroll
        for (int ks = 0; ks < 2; ks++)
          kf[tt][ks] = *(const bf16x8*)(Kbb + ((size_t)(tn + tt * 16 + lm)) * 64 + ks * 32 + kg * 8);
    }
    __syncthreads();
    f32x4 ri[2];
#pragma unroll
    for (int tt = 0; tt < 2; tt++) {
      const int rb = buf * 2368 + lm * 148 + tt * 16 + kg * 4;
      f32x4 s = *(f32x4*)&sden[rb] + *(f32x4*)&sden[rb + 36] +
                *(f32x4*)&sden[rb + 72] + *(f32x4*)&sden[rb + 108];
#pragma unroll
      for (int r = 0; r < 4; r++) ri[tt][r] = 1.f / s[r];
    }

    // P -> wave-private LDS [4 i][16 s][80B] bf16; read back as PV A-frags
#pragma unroll
    for (int i = 0; i < 4; i++)
#pragma unroll
      for (int tt = 0; tt < 2; tt++) {
        uint2 u;
        u.x = pkbf(ev[i][tt][0] * ri[tt][0], ev[i][tt][1] * ri[tt][1]);
        u.y = pkbf(ev[i][tt][2] * ri[tt][2], ev[i][tt][3] * ri[tt][3]);
        *(uint2*)(wv + i * 1280 + lm * 80 + tt * 32 + kg * 8) = u;
      }
    asm volatile("s_waitcnt lgkmcnt(0)" ::: "memory");
#pragma unroll
    for (int i = 0; i < 4; i++) {
      bf16x8 pa = *(bf16x8*)(wv + i * 1280 + lm * 80 + kg * 16);
#pragma unroll
      for (int dt = 0; dt < 4; dt++) pv[i][dt] = MFMA(pa, vf[dt], pv[i][dt]);
    }
    asm volatile("" ::: "memory");
    buf ^= 1;
  }

  // ---- epilogue: swizzled wave-LDS transpose -> coalesced bf16 stores
  const int orow = lane >> 2, oc4 = lane & 3;
#pragma unroll
  for (int i = 0; i < 4; i++) {
#pragma unroll
    for (int dt = 0; dt < 4; dt++)
#pragma unroll
      for (int r = 0; r < 4; r++) {
        int srow = kg * 4 + r;
        int cb = (dt * 16 + lm) * 4;
        *(float*)(wv + srow * 256 + (cb ^ ((srow & 7) << 4))) = pv[i][dt][r];
      }
    asm volatile("s_waitcnt lgkmcnt(0)" ::: "memory");
    float4 o0 = *(float4*)(wv + orow * 256 + ((oc4 * 64 + 0) ^ ((orow & 7) << 4)));
    float4 o1 = *(float4*)(wv + orow * 256 + ((oc4 * 64 + 16) ^ ((orow & 7) << 4)));
    float4 o2 = *(float4*)(wv + orow * 256 + ((oc4 * 64 + 32) ^ ((orow & 7) << 4)));
    float4 o3 = *(float4*)(wv + orow * 256 + ((oc4 * 64 + 48) ^ ((orow & 7) << 4)));
    __hip_bfloat16* dst = dvp + (size_t)tc * N4 +
                          ((size_t)((b * HH + w * 4 + i) * SS) + s0 + orow) * 64 + oc4 * 16;
    *(bf16x8*)dst = pack8(o0, o1);
    *(bf16x8*)(dst + 8) = pack8(o2, o3);
    asm volatile("" ::: "memory");
  }
}

// ---- k3: dv = p0+p1+p2+p3 (written in-place to p0 as bf16); column exp-sum partials
// (sdv is recomputed in k_final from the rounded dv; csum uses the same rounded dv)
__global__ __launch_bounds__(256) void k_rowsm(__hip_bfloat16* __restrict__ dvp,
                                               float* __restrict__ csum) {
  const int tid = threadIdx.x, w = tid >> 6, lane = tid & 63;
  const int rr = lane >> 4, dl = lane & 15;
  const int r0 = blockIdx.x * 64 + w * 16;
  const __hip_bfloat16* p1 = dvp + (size_t)N4;
  const __hip_bfloat16* p2 = dvp + (size_t)2 * N4;
  const __hip_bfloat16* p3 = dvp + (size_t)3 * N4;
  float cs0 = 0.f, cs1 = 0.f, cs2 = 0.f, cs3 = 0.f;
#pragma unroll
  for (int it = 0; it < 4; it++) {
    int r = r0 + it * 4 + rr;
    size_t off = (size_t)r * 64 + dl * 4;
    ushort4 ua = *(const ushort4*)(dvp + off);
    ushort4 ub = *(const ushort4*)(p1 + off);
    ushort4 uc = *(const ushort4*)(p2 + off);
    ushort4 ud = *(const ushort4*)(p3 + off);
    ushort4 uo;
    uo.x = f2b((b2f(ua.x) + b2f(ub.x)) + (b2f(uc.x) + b2f(ud.x)));
    uo.y = f2b((b2f(ua.y) + b2f(ub.y)) + (b2f(uc.y) + b2f(ud.y)));
    uo.z = f2b((b2f(ua.z) + b2f(ub.z)) + (b2f(uc.z) + b2f(ud.z)));
    uo.w = f2b((b2f(ua.w) + b2f(ub.w)) + (b2f(uc.w) + b2f(ud.w)));
    *(ushort4*)(dvp + off) = uo;  // in-place dv sum (per-thread, no hazard)
    // row-softmax over D from the ROUNDED dv (exactly what k_final recomputes)
    float d0 = b2f(uo.x), d1 = b2f(uo.y), d2 = b2f(uo.z), d3 = b2f(uo.w);
    float e0 = exp2f(d0 * L2E), e1 = exp2f(d1 * L2E);
    float e2 = exp2f(d2 * L2E), e3 = exp2f(d3 * L2E);
    float s = (e0 + e1) + (e2 + e3);
    s += __shfl_xor(s, 1); s += __shfl_xor(s, 2); s += __shfl_xor(s, 4); s += __shfl_xor(s, 8);
    float rv = 1.f / s;
    cs0 += exp2f(e0 * rv * L2E); cs1 += exp2f(e1 * rv * L2E);
    cs2 += exp2f(e2 * rv * L2E); cs3 += exp2f(e3 * rv * L2E);
  }
  cs0 += __shfl_xor(cs0, 16); cs0 += __shfl_xor(cs0, 32);
  cs1 += __shfl_xor(cs1, 16); cs1 += __shfl_xor(cs1, 32);
  cs2 += __shfl_xor(cs2, 16); cs2 += __shfl_xor(cs2, 32);
  cs3 += __shfl_xor(cs3, 16); cs3 += __shfl_xor(cs3, 32);
  __shared__ float red[4][64];
  if (rr == 0) {
    red[w][dl * 4 + 0] = cs0; red[w][dl * 4 + 1] = cs1;
    red[w][dl * 4 + 2] = cs2; red[w][dl * 4 + 3] = cs3;
  }
  __syncthreads();
  if (tid < 64)
    csum[(size_t)blockIdx.x * 64 + tid] = (red[0][tid] + red[1][tid]) + (red[2][tid] + red[3][tid]);
}

// ---- k4: combine column exp-sums; recompute row-softmax; out = exp(sdv)/L * dv
__global__ __launch_bounds__(256) void k_final(const __hip_bfloat16* __restrict__ dvs,
                                               const float* __restrict__ csum,
                                               float* __restrict__ out) {
  const int tid = threadIdx.x, w = tid >> 6, lane = tid & 63;
  const int rr = lane >> 4, dl = lane & 15;
  __shared__ float rL[64];
  if (tid < 64) {
    int bh = blockIdx.x >> 4;
    float L = 0.f;
#pragma unroll
    for (int c = 0; c < 16; c++) L += csum[((size_t)bh * 16 + c) * 64 + tid];
    rL[tid] = 1.f / L;
  }
  __syncthreads();
  const int r0 = blockIdx.x * 64 + w * 16;
#pragma unroll
  for (int it = 0; it < 4; it++) {
    int r = r0 + it * 4 + rr;
    size_t off = (size_t)r * 64 + dl * 4;
    ushort4 u = *(const ushort4*)(dvs + off);
    float d0 = b2f(u.x), d1 = b2f(u.y), d2 = b2f(u.z), d3 = b2f(u.w);
    float e0 = exp2f(d0 * L2E), e1 = exp2f(d1 * L2E);
    float e2 = exp2f(d2 * L2E), e3 = exp2f(d3 * L2E);
    float s = (e0 + e1) + (e2 + e3);
    s += __shfl_xor(s, 1); s += __shfl_xor(s, 2); s += __shfl_xor(s, 4); s += __shfl_xor(s, 8);
    float rv = 1.f / s;
    float4 o;
    o.x = exp2f(e0 * rv * L2E) * rL[dl * 4 + 0] * d0;
    o.y = exp2f(e1 * rv * L2E) * rL[dl * 4 + 1] * d1;
    o.z = exp2f(e2 * rv * L2E) * rL[dl * 4 + 2] * d2;
    o.w = exp2f(e3 * rv * L2E) * rL[dl * 4 + 3] * d3;
    *(float4*)(out + off) = o;
  }
}

extern "C" void kernel_launch(void* const* d_in, const int* in_sizes, int n_in,
                              void* d_out, int out_size, void* d_ws, size_t ws_size,
                              hipStream_t stream) {
  const float* query = (const float*)d_in[0];
  const float* key = (const float*)d_in[1];
  const float* value = (const float*)d_in[2];
  const float* weight = (const float*)d_in[3];
  const float* scale = (const float*)d_in[4];
  float* out = (float*)d_out;

  char* wsb = (char*)d_ws;
  __hip_bfloat16* dvp = (__hip_bfloat16*)wsb;               // 4*N4 bf16 = 32 MB
  __hip_bfloat16* Kb = (__hip_bfloat16*)(wsb + 33554432);   // 512 KB
  __hip_bfloat16* VTb = (__hip_bfloat16*)(wsb + 34078720);  // 512 KB
  __hip_bfloat16* WT = (__hip_bfloat16*)(wsb + 34603008);   // 128 KB
  float* csum = (float*)(wsb + 34731008);                   // 256 KB

  k_prep<<<144, 256, 0, stream>>>(key, value, weight, Kb, VTb, WT);
  k_attn<<<dim3(4, 64, 4), 256, 0, stream>>>(query, Kb, VTb, WT, scale, dvp);
  k_rowsm<<<1024, 256, 0, stream>>>(dvp, csum);
  k_final<<<1024, 256, 0, stream>>>(dvp, csum, out);
}

// Round 10
// 143.479 us; speedup vs baseline: 1.5448x; 1.5448x over previous
//
#include <hip/hip_runtime.h>
#include <hip/hip_bf16.h>

#define BB 4
#define HH 16
#define SS 1024
#define DD 64
#define N4 4194304  // B*H*S*D
#define L2E 1.44269504f

typedef __attribute__((ext_vector_type(8))) short bf16x8;
typedef __attribute__((ext_vector_type(4))) float f32x4;

#define MFMA(A, B, C) __builtin_amdgcn_mfma_f32_16x16x32_bf16((A), (B), (C), 0, 0, 0)

__device__ inline float b2f(unsigned short u) { return __uint_as_float(((unsigned)u) << 16); }
__device__ inline unsigned short f2b(float f) {
  union { __hip_bfloat16 h; unsigned short u; } x;
  x.h = __float2bfloat16(f);
  return x.u;
}
__device__ inline unsigned pkbf(float a, float b) {
  return (unsigned)f2b(a) | ((unsigned)f2b(b) << 16);
}
__device__ inline bf16x8 pack8(float4 a, float4 b) {
  union { bf16x8 v; unsigned short u[8]; } x;
  x.u[0] = f2b(a.x); x.u[1] = f2b(a.y); x.u[2] = f2b(a.z); x.u[3] = f2b(a.w);
  x.u[4] = f2b(b.x); x.u[5] = f2b(b.y); x.u[6] = f2b(b.z); x.u[7] = f2b(b.w);
  return x.v;
}

// ---- k_prep: K->bf16 [b][t][d]; V->bf16 transposed [b][d][t]; W->bf16 transposed [h][e][d]
// grid 144 = 64 K-convert + 64 V-transpose + 16 W-transpose
__global__ __launch_bounds__(256) void k_prep(const float* __restrict__ key, const float* __restrict__ val,
                                              const float* __restrict__ wgt, __hip_bfloat16* __restrict__ Kb,
                                              __hip_bfloat16* __restrict__ VTb, __hip_bfloat16* __restrict__ WT) {
  const int bid = blockIdx.x, tid = threadIdx.x;
  if (bid < 64) {  // K convert: 64 blocks x 4096 elems
    size_t base = (size_t)bid * 4096 + (size_t)tid * 16;
#pragma unroll
    for (int j = 0; j < 4; j++) {
      float4 v = *(const float4*)(key + base + j * 4);
      ushort4 u;
      u.x = f2b(v.x); u.y = f2b(v.y); u.z = f2b(v.z); u.w = f2b(v.w);
      *(ushort4*)(Kb + base + j * 4) = u;
    }
    return;
  }
  __shared__ __hip_bfloat16 tl[64][72];
  const float* src;
  __hip_bfloat16* dst;
  int dstride;
  if (bid < 128) {  // V transpose: 64 blocks of 64x64 tiles
    int qq = bid - 64;
    int b2 = qq >> 4, t0 = (qq & 15) * 64;
    src = val + ((size_t)b2 * 1024 + t0) * 64;
    dst = VTb + (size_t)b2 * 65536 + t0;
    dstride = 1024;
  } else {  // W transpose per head: 16 blocks
    int h = bid - 128;
    src = wgt + (size_t)h * 4096;
    dst = WT + (size_t)h * 4096;
    dstride = 64;
  }
  int row = tid >> 2, cq = (tid & 3) * 16;
#pragma unroll
  for (int j = 0; j < 4; j++) {
    float4 v = *(const float4*)(src + (size_t)row * 64 + cq + j * 4);
    tl[cq + j * 4 + 0][row] = __float2bfloat16(v.x);
    tl[cq + j * 4 + 1][row] = __float2bfloat16(v.y);
    tl[cq + j * 4 + 2][row] = __float2bfloat16(v.z);
    tl[cq + j * 4 + 3][row] = __float2bfloat16(v.w);
  }
  __syncthreads();
#pragma unroll
  for (int j = 0; j < 2; j++) {
    bf16x8 a = *(bf16x8*)&tl[row][cq + j * 8];
    *(bf16x8*)(dst + (size_t)row * dstride + cq + j * 8) = a;
  }
}

// ---- k_attn: fused wq-proj + qk^T (MFMA) + cross-head softmax + PV (MFMA)
// block = (b, s-tile 16, t-chunk 256); 4 waves; wave w owns heads 4w..4w+3.
// launch_bounds (256,2): round-7-measured 108 VGPR no-spill; (256,4) forced a
// 64-VGPR allocation with catastrophic scratch spill (round 9: 470MB traffic).
// Natural 108 VGPR -> 4 waves/EU; LDS 39424x4 = 157.7KB -> 4 blocks/CU anyway.
__global__ __launch_bounds__(256, 2) void k_attn(
    const float* __restrict__ q, const __hip_bfloat16* __restrict__ Kb,
    const __hip_bfloat16* __restrict__ VTb, const __hip_bfloat16* __restrict__ WT,
    const float* __restrict__ scale_p, __hip_bfloat16* __restrict__ dvp) {
  const int b = blockIdx.x, s0 = blockIdx.y << 4, tc = blockIdx.z;
  const int tid = threadIdx.x, lane = tid & 63, w = tid >> 6;
  const int lm = lane & 15, kg = lane >> 4;
  const float csl = (*scale_p) * L2E;

  __shared__ __align__(16) char smem_all[39424];
  float* sden = (float*)smem_all;              // 18944 B
  char* wv = smem_all + 18944 + w * 5120;      // wave-private 5120 B

  // ---- prologue: q B-frags (lane lm = s, k = d)
  bf16x8 qf[2];
#pragma unroll
  for (int ks = 0; ks < 2; ks++) {
    const float* qp = q + ((size_t)(b * SS + s0 + lm)) * DD + ks * 32 + kg * 8;
    qf[ks] = pack8(*(const float4*)qp, *(const float4*)(qp + 4));
  }
  // wq^T = mfma(WT, q) * scale * log2e: D row=e, col=s -> wave-LDS (XOR-swizzled) -> B-frags
  bf16x8 wqf[4][2];
#pragma unroll
  for (int i = 0; i < 4; i++) {
    const int h = w * 4 + i;
    f32x4 wd[4];
#pragma unroll
    for (int et = 0; et < 4; et++) wd[et] = (f32x4){0.f, 0.f, 0.f, 0.f};
#pragma unroll
    for (int et = 0; et < 4; et++)
#pragma unroll
      for (int ks = 0; ks < 2; ks++) {
        bf16x8 af = *(const bf16x8*)(WT + ((size_t)(h * 64 + et * 16 + lm)) * 64 + ks * 32 + kg * 8);
        wd[et] = MFMA(af, qf[ks], wd[et]);
      }
#pragma unroll
    for (int et = 0; et < 4; et++) {
      uint2 u;
      u.x = pkbf(wd[et][0] * csl, wd[et][1] * csl);
      u.y = pkbf(wd[et][2] * csl, wd[et][3] * csl);
      *(uint2*)(wv + lm * 128 + ((et * 32 + kg * 8) ^ ((lm & 7) << 4))) = u;
    }
    asm volatile("s_waitcnt lgkmcnt(0)" ::: "memory");
#pragma unroll
    for (int ks = 0; ks < 2; ks++)
      wqf[i][ks] = *(bf16x8*)(wv + lm * 128 + ((ks * 64 + kg * 16) ^ ((lm & 7) << 4)));
    asm volatile("" ::: "memory");
  }

  // ---- main loop over 32-t tiles (8 per chunk)
  f32x4 pv[4][4];
#pragma unroll
  for (int i = 0; i < 4; i++)
#pragma unroll
    for (int dt = 0; dt < 4; dt++) pv[i][dt] = (f32x4){0.f, 0.f, 0.f, 0.f};

  const __hip_bfloat16* Kbb = Kb + (size_t)b * (SS * DD);
  const __hip_bfloat16* Vbb = VTb + (size_t)b * (SS * DD);
  const int tbeg = tc * 256, tend = tbeg + 256;
  int buf = 0;
  bf16x8 kf[2][2], vf[4];
  // preload kf for first tile
#pragma unroll
  for (int tt = 0; tt < 2; tt++)
#pragma unroll
    for (int ks = 0; ks < 2; ks++)
      kf[tt][ks] = *(const bf16x8*)(Kbb + ((size_t)(tbeg + tt * 16 + lm)) * 64 + ks * 32 + kg * 8);

#pragma unroll 1
  for (int t0 = tbeg; t0 < tend; t0 += 32) {
    // vf for current tile (consumed at PV; latency covered by QK/exp phases + barrier)
#pragma unroll
    for (int dt = 0; dt < 4; dt++)
      vf[dt] = *(const bf16x8*)(Vbb + ((size_t)(dt * 16 + lm)) * 1024 + t0 + kg * 8);

    // qk^T: D row = t (4kg+r within tt), col = s (lm); scale pre-folded
    f32x4 qk[4][2];
#pragma unroll
    for (int i = 0; i < 4; i++)
#pragma unroll
      for (int tt = 0; tt < 2; tt++) qk[i][tt] = (f32x4){0.f, 0.f, 0.f, 0.f};
#pragma unroll
    for (int ks = 0; ks < 2; ks++)
#pragma unroll
      for (int i = 0; i < 4; i++)
#pragma unroll
        for (int tt = 0; tt < 2; tt++) qk[i][tt] = MFMA(kf[tt][ks], wqf[i][ks], qk[i][tt]);

    // e = exp2(qk), per-wave partial sums over 4 local heads (no max-sub: |qk| small)
    float ev[4][2][4];
    f32x4 l4[2];
    l4[0] = (f32x4){0.f, 0.f, 0.f, 0.f};
    l4[1] = (f32x4){0.f, 0.f, 0.f, 0.f};
#pragma unroll
    for (int i = 0; i < 4; i++)
#pragma unroll
      for (int tt = 0; tt < 2; tt++)
#pragma unroll
        for (int r = 0; r < 4; r++) {
          float e = exp2f(qk[i][tt][r]);
          ev[i][tt][r] = e;
          l4[tt][r] += e;
        }
    {
      // t = tt*16 + kg*4 + r
      const int sb = buf * 2368 + lm * 148 + w * 36 + kg * 4;
      *(f32x4*)&sden[sb + 0] = l4[0];
      *(f32x4*)&sden[sb + 16] = l4[1];
    }
    // prefetch kf for next tile (wraps on last iter; barrier drain absorbs latency)
    {
      int tn = (t0 + 32 < tend) ? t0 + 32 : tbeg;
#pragma unroll
      for (int tt = 0; tt < 2; tt++)
#pragma unroll
        for (int ks = 0; ks < 2; ks++)
          kf[tt][ks] = *(const bf16x8*)(Kbb + ((size_t)(tn + tt * 16 + lm)) * 64 + ks * 32 + kg * 8);
    }
    __syncthreads();
    f32x4 ri[2];
#pragma unroll
    for (int tt = 0; tt < 2; tt++) {
      const int rb = buf * 2368 + lm * 148 + tt * 16 + kg * 4;
      f32x4 s = *(f32x4*)&sden[rb] + *(f32x4*)&sden[rb + 36] +
                *(f32x4*)&sden[rb + 72] + *(f32x4*)&sden[rb + 108];
#pragma unroll
      for (int r = 0; r < 4; r++) ri[tt][r] = 1.f / s[r];
    }

    // P -> wave-private LDS [4 i][16 s][80B] bf16; read back as PV A-frags
#pragma unroll
    for (int i = 0; i < 4; i++)
#pragma unroll
      for (int tt = 0; tt < 2; tt++) {
        uint2 u;
        u.x = pkbf(ev[i][tt][0] * ri[tt][0], ev[i][tt][1] * ri[tt][1]);
        u.y = pkbf(ev[i][tt][2] * ri[tt][2], ev[i][tt][3] * ri[tt][3]);
        *(uint2*)(wv + i * 1280 + lm * 80 + tt * 32 + kg * 8) = u;
      }
    asm volatile("s_waitcnt lgkmcnt(0)" ::: "memory");
#pragma unroll
    for (int i = 0; i < 4; i++) {
      bf16x8 pa = *(bf16x8*)(wv + i * 1280 + lm * 80 + kg * 16);
#pragma unroll
      for (int dt = 0; dt < 4; dt++) pv[i][dt] = MFMA(pa, vf[dt], pv[i][dt]);
    }
    asm volatile("" ::: "memory");
    buf ^= 1;
  }

  // ---- epilogue: swizzled wave-LDS transpose -> coalesced bf16 stores
  const int orow = lane >> 2, oc4 = lane & 3;
#pragma unroll
  for (int i = 0; i < 4; i++) {
#pragma unroll
    for (int dt = 0; dt < 4; dt++)
#pragma unroll
      for (int r = 0; r < 4; r++) {
        int srow = kg * 4 + r;
        int cb = (dt * 16 + lm) * 4;
        *(float*)(wv + srow * 256 + (cb ^ ((srow & 7) << 4))) = pv[i][dt][r];
      }
    asm volatile("s_waitcnt lgkmcnt(0)" ::: "memory");
    float4 o0 = *(float4*)(wv + orow * 256 + ((oc4 * 64 + 0) ^ ((orow & 7) << 4)));
    float4 o1 = *(float4*)(wv + orow * 256 + ((oc4 * 64 + 16) ^ ((orow & 7) << 4)));
    float4 o2 = *(float4*)(wv + orow * 256 + ((oc4 * 64 + 32) ^ ((orow & 7) << 4)));
    float4 o3 = *(float4*)(wv + orow * 256 + ((oc4 * 64 + 48) ^ ((orow & 7) << 4)));
    __hip_bfloat16* dst = dvp + (size_t)tc * N4 +
                          ((size_t)((b * HH + w * 4 + i) * SS) + s0 + orow) * 64 + oc4 * 16;
    *(bf16x8*)dst = pack8(o0, o1);
    *(bf16x8*)(dst + 8) = pack8(o2, o3);
    asm volatile("" ::: "memory");
  }
}

// ---- k3: dv = p0+p1+p2+p3 (written in-place to p0 as bf16); column exp-sum partials
// (sdv is recomputed in k_final from the rounded dv; csum uses the same rounded dv)
__global__ __launch_bounds__(256) void k_rowsm(__hip_bfloat16* __restrict__ dvp,
                                               float* __restrict__ csum) {
  const int tid = threadIdx.x, w = tid >> 6, lane = tid & 63;
  const int rr = lane >> 4, dl = lane & 15;
  const int r0 = blockIdx.x * 64 + w * 16;
  const __hip_bfloat16* p1 = dvp + (size_t)N4;
  const __hip_bfloat16* p2 = dvp + (size_t)2 * N4;
  const __hip_bfloat16* p3 = dvp + (size_t)3 * N4;
  float cs0 = 0.f, cs1 = 0.f, cs2 = 0.f, cs3 = 0.f;
#pragma unroll
  for (int it = 0; it < 4; it++) {
    int r = r0 + it * 4 + rr;
    size_t off = (size_t)r * 64 + dl * 4;
    ushort4 ua = *(const ushort4*)(dvp + off);
    ushort4 ub = *(const ushort4*)(p1 + off);
    ushort4 uc = *(const ushort4*)(p2 + off);
    ushort4 ud = *(const ushort4*)(p3 + off);
    ushort4 uo;
    uo.x = f2b((b2f(ua.x) + b2f(ub.x)) + (b2f(uc.x) + b2f(ud.x)));
    uo.y = f2b((b2f(ua.y) + b2f(ub.y)) + (b2f(uc.y) + b2f(ud.y)));
    uo.z = f2b((b2f(ua.z) + b2f(ub.z)) + (b2f(uc.z) + b2f(ud.z)));
    uo.w = f2b((b2f(ua.w) + b2f(ub.w)) + (b2f(uc.w) + b2f(ud.w)));
    *(ushort4*)(dvp + off) = uo;  // in-place dv sum (per-thread, no hazard)
    // row-softmax over D from the ROUNDED dv (exactly what k_final recomputes)
    float d0 = b2f(uo.x), d1 = b2f(uo.y), d2 = b2f(uo.z), d3 = b2f(uo.w);
    float e0 = exp2f(d0 * L2E), e1 = exp2f(d1 * L2E);
    float e2 = exp2f(d2 * L2E), e3 = exp2f(d3 * L2E);
    float s = (e0 + e1) + (e2 + e3);
    s += __shfl_xor(s, 1); s += __shfl_xor(s, 2); s += __shfl_xor(s, 4); s += __shfl_xor(s, 8);
    float rv = 1.f / s;
    cs0 += exp2f(e0 * rv * L2E); cs1 += exp2f(e1 * rv * L2E);
    cs2 += exp2f(e2 * rv * L2E); cs3 += exp2f(e3 * rv * L2E);
  }
  cs0 += __shfl_xor(cs0, 16); cs0 += __shfl_xor(cs0, 32);
  cs1 += __shfl_xor(cs1, 16); cs1 += __shfl_xor(cs1, 32);
  cs2 += __shfl_xor(cs2, 16); cs2 += __shfl_xor(cs2, 32);
  cs3 += __shfl_xor(cs3, 16); cs3 += __shfl_xor(cs3, 32);
  __shared__ float red[4][64];
  if (rr == 0) {
    red[w][dl * 4 + 0] = cs0; red[w][dl * 4 + 1] = cs1;
    red[w][dl * 4 + 2] = cs2; red[w][dl * 4 + 3] = cs3;
  }
  __syncthreads();
  if (tid < 64)
    csum[(size_t)blockIdx.x * 64 + tid] = (red[0][tid] + red[1][tid]) + (red[2][tid] + red[3][tid]);
}

// ---- k4: combine column exp-sums; recompute row-softmax; out = exp(sdv)/L * dv
__global__ __launch_bounds__(256) void k_final(const __hip_bfloat16* __restrict__ dvs,
                                               const float* __restrict__ csum,
                                               float* __restrict__ out) {
  const int tid = threadIdx.x, w = tid >> 6, lane = tid & 63;
  const int rr = lane >> 4, dl = lane & 15;
  __shared__ float rL[64];
  if (tid < 64) {
    int bh = blockIdx.x >> 4;
    float L = 0.f;
#pragma unroll
    for (int c = 0; c < 16; c++) L += csum[((size_t)bh * 16 + c) * 64 + tid];
    rL[tid] = 1.f / L;
  }
  __syncthreads();
  const int r0 = blockIdx.x * 64 + w * 16;
#pragma unroll
  for (int it = 0; it < 4; it++) {
    int r = r0 + it * 4 + rr;
    size_t off = (size_t)r * 64 + dl * 4;
    ushort4 u = *(const ushort4*)(dvs + off);
    float d0 = b2f(u.x), d1 = b2f(u.y), d2 = b2f(u.z), d3 = b2f(u.w);
    float e0 = exp2f(d0 * L2E), e1 = exp2f(d1 * L2E);
    float e2 = exp2f(d2 * L2E), e3 = exp2f(d3 * L2E);
    float s = (e0 + e1) + (e2 + e3);
    s += __shfl_xor(s, 1); s += __shfl_xor(s, 2); s += __shfl_xor(s, 4); s += __shfl_xor(s, 8);
    float rv = 1.f / s;
    float4 o;
    o.x = exp2f(e0 * rv * L2E) * rL[dl * 4 + 0] * d0;
    o.y = exp2f(e1 * rv * L2E) * rL[dl * 4 + 1] * d1;
    o.z = exp2f(e2 * rv * L2E) * rL[dl * 4 + 2] * d2;
    o.w = exp2f(e3 * rv * L2E) * rL[dl * 4 + 3] * d3;
    *(float4*)(out + off) = o;
  }
}

extern "C" void kernel_launch(void* const* d_in, const int* in_sizes, int n_in,
                              void* d_out, int out_size, void* d_ws, size_t ws_size,
                              hipStream_t stream) {
  const float* query = (const float*)d_in[0];
  const float* key = (const float*)d_in[1];
  const float* value = (const float*)d_in[2];
  const float* weight = (const float*)d_in[3];
  const float* scale = (const float*)d_in[4];
  float* out = (float*)d_out;

  char* wsb = (char*)d_ws;
  __hip_bfloat16* dvp = (__hip_bfloat16*)wsb;               // 4*N4 bf16 = 32 MB
  __hip_bfloat16* Kb = (__hip_bfloat16*)(wsb + 33554432);   // 512 KB
  __hip_bfloat16* VTb = (__hip_bfloat16*)(wsb + 34078720);  // 512 KB
  __hip_bfloat16* WT = (__hip_bfloat16*)(wsb + 34603008);   // 128 KB
  float* csum = (float*)(wsb + 34731008);                   // 256 KB

  k_prep<<<144, 256, 0, stream>>>(key, value, weight, Kb, VTb, WT);
  k_attn<<<dim3(4, 64, 4), 256, 0, stream>>>(query, Kb, VTb, WT, scale, dvp);
  k_rowsm<<<1024, 256, 0, stream>>>(dvp, csum);
  k_final<<<1024, 256, 0, stream>>>(dvp, csum, out);
}